// Round 1
// baseline (421.468 us; speedup 1.0000x reference)
//
#include <hip/hip_runtime.h>
#include <math.h>

// GRU-D with diagonal (vector) weights: every op is elementwise over [B,F].
// Each (b,f) is an independent scalar recurrence over T steps -> one thread
// per (b,f), serial t-loop in registers, prefetch ring to hide HBM latency
// (only 1 wave/SIMD of TLP available, so ILP must do the hiding).

#define TT 512
#define BB 256
#define FF 256
#define PF_D 8   // prefetch ring depth: 24 loads in flight/thread

__device__ __forceinline__ float fast_sigmoid(float x) {
    return __builtin_amdgcn_rcpf(1.0f + __expf(-x));
}
__device__ __forceinline__ float fast_tanh(float x) {
    // tanh(x) = 1 - 2/(exp(2x)+1); saturates correctly at +/-inf.
    return fmaf(-2.0f, __builtin_amdgcn_rcpf(1.0f + __expf(2.0f * x)), 1.0f);
}

__global__ __launch_bounds__(256) void grud_kernel(
    const float* __restrict__ X, const float* __restrict__ Mask,
    const float* __restrict__ Delta,
    const float* __restrict__ x_mean,
    const float* __restrict__ w_dg_x, const float* __restrict__ b_dg_x,
    const float* __restrict__ w_dg_h, const float* __restrict__ b_dg_h,
    const float* __restrict__ w_xz, const float* __restrict__ u_hz,
    const float* __restrict__ b_z,
    const float* __restrict__ w_xr, const float* __restrict__ u_hr,
    const float* __restrict__ b_r,
    const float* __restrict__ w_xh, const float* __restrict__ u_hh,
    const float* __restrict__ v_mh, const float* __restrict__ b_h,
    float* __restrict__ out)
{
    const int g = blockIdx.x * blockDim.x + threadIdx.x;  // g = b*F + f
    const int f = g & (FF - 1);
    const int b = g >> 8;

    // Per-feature parameters (one coalesced load each, L2-resident).
    const float xm  = x_mean[f];
    const float wdx = w_dg_x[f], bdx = b_dg_x[f];
    const float wdh = w_dg_h[f], bdh = b_dg_h[f];
    const float wxz = w_xz[f],   uhz = u_hz[f], bz = b_z[f];
    const float wxr = w_xr[f],   uhr = u_hr[f], br = b_r[f];
    const float wxh = w_xh[f],   uhh = u_hh[f];
    const float vmh = v_mh[f],   bh  = b_h[f];

    const float* xp = X     + g;   // stride B*F per t
    const float* mp = Mask  + g;
    const float* dp = Delta + g;
    float* op = out + (size_t)b * (TT * FF) + f;  // stride F per t

    // ---- prefetch ring ----
    float px[PF_D], pm[PF_D], pd[PF_D];
    #pragma unroll
    for (int i = 0; i < PF_D; ++i) {
        px[i] = xp[i * (BB * FF)];
        pm[i] = mp[i * (BB * FF)];
        pd[i] = dp[i * (BB * FF)];
    }

    float h = 0.0f;

    // main loop: consume slot t%D, refill with t+D
    #pragma unroll PF_D
    for (int t = 0; t < TT - PF_D; ++t) {
        const int slot = t & (PF_D - 1);
        float x = px[slot], m = pm[slot], d = pd[slot];
        const int tn = t + PF_D;
        px[slot] = xp[tn * (BB * FF)];
        pm[slot] = mp[tn * (BB * FF)];
        pd[slot] = dp[tn * (BB * FF)];

        float gx = __expf(-fmaxf(0.0f, fmaf(wdx, d, bdx)));
        float gh = __expf(-fmaxf(0.0f, fmaf(wdh, d, bdh)));
        float xhat = fmaf(gx, x, (1.0f - gx) * xm);
        x = fmaf(m, x, (1.0f - m) * xhat);
        h = gh * h;
        float z  = fast_sigmoid(fmaf(wxz, x, fmaf(uhz, h, bz)));
        float r  = fast_sigmoid(fmaf(wxr, x, fmaf(uhr, h, br)));
        float ht = fast_tanh(fmaf(wxh, x, fmaf(uhh, r * h, fmaf(vmh, m, bh))));
        h = fmaf(z, ht - h, h);   // (1-z)*h + z*ht
        op[t * FF] = h;
    }

    // tail: drain the ring, no more prefetch
    #pragma unroll
    for (int t = TT - PF_D; t < TT; ++t) {
        const int slot = t & (PF_D - 1);
        float x = px[slot], m = pm[slot], d = pd[slot];

        float gx = __expf(-fmaxf(0.0f, fmaf(wdx, d, bdx)));
        float gh = __expf(-fmaxf(0.0f, fmaf(wdh, d, bdh)));
        float xhat = fmaf(gx, x, (1.0f - gx) * xm);
        x = fmaf(m, x, (1.0f - m) * xhat);
        h = gh * h;
        float z  = fast_sigmoid(fmaf(wxz, x, fmaf(uhz, h, bz)));
        float r  = fast_sigmoid(fmaf(wxr, x, fmaf(uhr, h, br)));
        float ht = fast_tanh(fmaf(wxh, x, fmaf(uhh, r * h, fmaf(vmh, m, bh))));
        h = fmaf(z, ht - h, h);
        op[t * FF] = h;
    }

    // second output: last hidden state [B, H]
    out[(size_t)BB * TT * FF + g] = h;
}

extern "C" void kernel_launch(void* const* d_in, const int* in_sizes, int n_in,
                              void* d_out, int out_size, void* d_ws, size_t ws_size,
                              hipStream_t stream) {
    const float* X      = (const float*)d_in[0];
    const float* Mask   = (const float*)d_in[1];
    const float* Delta  = (const float*)d_in[2];
    const float* x_mean = (const float*)d_in[3];
    const float* w_dg_x = (const float*)d_in[4];
    const float* b_dg_x = (const float*)d_in[5];
    const float* w_dg_h = (const float*)d_in[6];
    const float* b_dg_h = (const float*)d_in[7];
    const float* w_xz   = (const float*)d_in[8];
    const float* u_hz   = (const float*)d_in[9];
    const float* b_z    = (const float*)d_in[10];
    const float* w_xr   = (const float*)d_in[11];
    const float* u_hr   = (const float*)d_in[12];
    const float* b_r    = (const float*)d_in[13];
    const float* w_xh   = (const float*)d_in[14];
    const float* u_hh   = (const float*)d_in[15];
    const float* v_mh   = (const float*)d_in[16];
    const float* b_h    = (const float*)d_in[17];
    float* out = (float*)d_out;

    const int threads = BB * FF;       // 65536: one per (b,f)
    grud_kernel<<<threads / 256, 256, 0, stream>>>(
        X, Mask, Delta, x_mean, w_dg_x, b_dg_x, w_dg_h, b_dg_h,
        w_xz, u_hz, b_z, w_xr, u_hr, b_r, w_xh, u_hh, v_mh, b_h, out);
}

// Round 2
// 417.583 us; speedup vs baseline: 1.0093x; 1.0093x over previous
//
#include <hip/hip_runtime.h>
#include <math.h>

// GRU-D, diagonal weights: independent scalar recurrence per (b,f) over T.
// R1: producer/consumer wave specialization. Problem parallelism caps compute
// at 1 wave/SIMD; the serial h-chain can't hide HBM latency alone. Waves 0-3
// compute from LDS; waves 4-7 stream X/Mask/Delta into a double-buffered LDS
// ring. Compute waves have zero global loads -> no vmcnt stalls in the chain.

#define TT 512
#define BB 256
#define FF 256
#define BF (BB * FF)        // 65536 elements per time step per array
#define CH 8                // steps per chunk
#define NCH (TT / CH)       // 32 chunks

__device__ __forceinline__ float fast_sigmoid(float x) {
    return __builtin_amdgcn_rcpf(1.0f + __expf(-x));
}
__device__ __forceinline__ float fast_tanh(float x) {
    return fmaf(-2.0f, __builtin_amdgcn_rcpf(1.0f + __expf(2.0f * x)), 1.0f);
}

__global__ __launch_bounds__(512) void grud_kernel(
    const float* __restrict__ X, const float* __restrict__ Mask,
    const float* __restrict__ Delta,
    const float* __restrict__ x_mean,
    const float* __restrict__ w_dg_x, const float* __restrict__ b_dg_x,
    const float* __restrict__ w_dg_h, const float* __restrict__ b_dg_h,
    const float* __restrict__ w_xz, const float* __restrict__ u_hz,
    const float* __restrict__ b_z,
    const float* __restrict__ w_xr, const float* __restrict__ u_hr,
    const float* __restrict__ b_r,
    const float* __restrict__ w_xh, const float* __restrict__ u_hh,
    const float* __restrict__ v_mh, const float* __restrict__ b_h,
    float* __restrict__ out)
{
    // [buf][arr][step][f] ; 2*3*8*256*4B = 48 KiB
    __shared__ float lds[2][3][CH][FF];

    const int tid = threadIdx.x;
    const int blk = blockIdx.x;          // batch index b; block covers all f

    if (tid >= 256) {
        // ---------------- loader waves ----------------
        const int j = tid - 256;                 // 0..255
        const float* srcs[3] = { X     + (size_t)blk * FF,
                                 Mask  + (size_t)blk * FF,
                                 Delta + (size_t)blk * FF };

        // prologue: chunk 0 -> buffer 0
        {
            #pragma unroll
            for (int arr = 0; arr < 3; ++arr) {
                const float* s = srcs[arr];
                #pragma unroll
                for (int i2 = 0; i2 < 2; ++i2) {
                    const int rem  = i2 * 256 + j;        // 0..511
                    const int step = rem >> 6;            // 0..7
                    const int f4   = (rem & 63) << 2;     // 0,4,..,252
                    *(float4*)&lds[0][arr][step][f4] =
                        *(const float4*)(s + (size_t)step * BF + f4);
                }
            }
        }
        __syncthreads();

        for (int k = 0; k < NCH; ++k) {
            if (k + 1 < NCH) {
                const int bufi = (k + 1) & 1;
                const int t0   = (k + 1) * CH;
                #pragma unroll
                for (int arr = 0; arr < 3; ++arr) {
                    const float* s = srcs[arr];
                    #pragma unroll
                    for (int i2 = 0; i2 < 2; ++i2) {
                        const int rem  = i2 * 256 + j;
                        const int step = rem >> 6;
                        const int f4   = (rem & 63) << 2;
                        *(float4*)&lds[bufi][arr][step][f4] =
                            *(const float4*)(s + (size_t)(t0 + step) * BF + f4);
                    }
                }
            }
            __syncthreads();
        }
    } else {
        // ---------------- compute waves ----------------
        const int f = tid;                        // 0..255
        const float xm  = x_mean[f];
        const float wdx = w_dg_x[f], bdx = b_dg_x[f];
        const float wdh = w_dg_h[f], bdh = b_dg_h[f];
        const float wxz = w_xz[f],   uhz = u_hz[f], bz = b_z[f];
        const float wxr = w_xr[f],   uhr = u_hr[f], br = b_r[f];
        const float wxh = w_xh[f],   uhh = u_hh[f];
        const float vmh = v_mh[f],   bh  = b_h[f];

        float h = 0.0f;
        __syncthreads();                          // matches loader prologue

        for (int k = 0; k < NCH; ++k) {
            const int cb = k & 1;
            float* op = out + ((size_t)blk * TT + (size_t)k * CH) * FF + f;
            #pragma unroll
            for (int s = 0; s < CH; ++s) {
                float x = lds[cb][0][s][f];
                float m = lds[cb][1][s][f];
                float d = lds[cb][2][s][f];

                float gx = __expf(-fmaxf(0.0f, fmaf(wdx, d, bdx)));
                float gh = __expf(-fmaxf(0.0f, fmaf(wdh, d, bdh)));
                float xhat = fmaf(gx, x, (1.0f - gx) * xm);
                x = fmaf(m, x, (1.0f - m) * xhat);
                h = gh * h;
                float z  = fast_sigmoid(fmaf(wxz, x, fmaf(uhz, h, bz)));
                float r  = fast_sigmoid(fmaf(wxr, x, fmaf(uhr, h, br)));
                float ht = fast_tanh(fmaf(wxh, x, fmaf(uhh, r * h, fmaf(vmh, m, bh))));
                h = fmaf(z, ht - h, h);           // (1-z)*h + z*ht
                op[s * FF] = h;
            }
            __syncthreads();
        }

        // second output: last hidden state [B, H]
        out[(size_t)BB * TT * FF + (size_t)blk * FF + f] = h;
    }
}

extern "C" void kernel_launch(void* const* d_in, const int* in_sizes, int n_in,
                              void* d_out, int out_size, void* d_ws, size_t ws_size,
                              hipStream_t stream) {
    const float* X      = (const float*)d_in[0];
    const float* Mask   = (const float*)d_in[1];
    const float* Delta  = (const float*)d_in[2];
    const float* x_mean = (const float*)d_in[3];
    const float* w_dg_x = (const float*)d_in[4];
    const float* b_dg_x = (const float*)d_in[5];
    const float* w_dg_h = (const float*)d_in[6];
    const float* b_dg_h = (const float*)d_in[7];
    const float* w_xz   = (const float*)d_in[8];
    const float* u_hz   = (const float*)d_in[9];
    const float* b_z    = (const float*)d_in[10];
    const float* w_xr   = (const float*)d_in[11];
    const float* u_hr   = (const float*)d_in[12];
    const float* b_r    = (const float*)d_in[13];
    const float* w_xh   = (const float*)d_in[14];
    const float* u_hh   = (const float*)d_in[15];
    const float* v_mh   = (const float*)d_in[16];
    const float* b_h    = (const float*)d_in[17];
    float* out = (float*)d_out;

    grud_kernel<<<BB, 512, 0, stream>>>(
        X, Mask, Delta, x_mean, w_dg_x, b_dg_x, w_dg_h, b_dg_h,
        w_xz, u_hz, b_z, w_xr, u_hr, b_r, w_xh, u_hh, v_mh, b_h, out);
}